// Round 12
// baseline (158.149 us; speedup 1.0000x reference)
//
#include <hip/hip_runtime.h>
#include <hip/hip_bf16.h>

// Two pairwise MLPs (ChG, DG) over 1024x1024 pairs, then A_chg @ A_gd, sigmoid.
// Outputs concat: [0:1M) sigmoid(A_chd), [1M:2M) A_chg, [2M:3M) A_gd (fp32).
//
// R12 = R9 structure (3 dispatches; R11's inline prep regressed +9us) with:
//  1. branch: in-loop divergent tail (elu/expf + cvt + 2 scattered stores,
//     quad==0) replaced by one ds_write of raw y to ybuf[pair][li] (stride 33,
//     conflict-free). Uniform block epilogue: elu once, coalesced float4/uint4
//     writes for outA (both branches) and outB (Achg direct, AgdT transposed
//     via ybuf -- replaces lds_t).
//  2. gemm_sig: BK=128 per LDS stage (8 barrier pairs instead of 16), 4 MFMA
//     per stage, dual acc; stride-136 LDS rows -> only 2-way bank aliasing.
// Numerics identical to R9: absmax must stay exactly 0.03125.

typedef _Float16 half8 __attribute__((ext_vector_type(8)));
typedef float floatx4 __attribute__((ext_vector_type(4)));
typedef float floatx2 __attribute__((ext_vector_type(2)));

union U4H8 { uint4 u; half8 h; };
union PKH8 { uint4 u; _Float16 h[8]; };

// ---------------------------------------------------------------- prep
// blocks 0..2047: hlhr (fp16): seg0 HL_chg(+b0c), seg1 HR_chg,
//                 seg2 HL_dg(+b0d), seg3 HR_dg; each [1024][128]
// blocks 2048..2111: w1frag[br][f=mt*4+ks][lane][j] =
//                 f16( W1[ks*32+(lane>>4)*8+j][mt*16+(lane&15)] )  (A-layout of W1^T)
__global__ __launch_bounds__(256) void prep(
    const float* __restrict__ Xch, const float* __restrict__ Xg,
    const float* __restrict__ Xd,
    const float* __restrict__ Wc0, const float* __restrict__ bc0,
    const float* __restrict__ Wd0, const float* __restrict__ bd0,
    const float* __restrict__ W1c, const float* __restrict__ W1d,
    _Float16* __restrict__ hlhr, _Float16* __restrict__ w1frag)
{
    int bid = blockIdx.x;
    if (bid < 2048) {
        int t = bid * 256 + threadIdx.x;   // 524288 threads
        int seg = t >> 17;
        int i = (t >> 7) & 1023;
        int k = t & 127;
        const float* X;
        const float* W;
        float s = 0.f;
        int wo = 0;
        if (seg == 0)      { X = Xch; W = Wc0; s = bc0[k]; }
        else if (seg == 1) { X = Xg;  W = Wc0; wo = 5; }
        else if (seg == 2) { X = Xg;  W = Wd0; s = bd0[k]; }
        else               { X = Xd;  W = Wd0; wo = 5; }
#pragma unroll
        for (int j = 0; j < 5; ++j)
            s += X[i * 5 + j] * W[(wo + j) * 128 + k];
        hlhr[t] = (_Float16)s;   // fp32 dot, one RNE round to fp16
    } else {
        int t = (bid - 2048) * 256 + threadIdx.x;   // 16384 threads
        int br   = t >> 13;
        int f    = (t >> 9) & 15;
        int lane = (t >> 3) & 63;
        int j    = t & 7;
        int mt = f >> 2, ks = f & 3;
        int row = ks * 32 + (lane >> 4) * 8 + j;    // k of W1
        int col = mt * 16 + (lane & 15);            // n of W1
        const float* W = br ? W1d : W1c;
        w1frag[t] = (_Float16)W[row * 64 + col];
    }
}

// ---------------------------------------------------------------- branch
#define LC 32
#define YSTRIDE 33   // ybuf row stride in floats (conflict-free)

__global__ __launch_bounds__(256, 3) void branch_kernel(
    const _Float16* __restrict__ hlhr,
    const float* __restrict__ b1_chg, const float* __restrict__ wr_chg, const float* __restrict__ br_chg,
    const float* __restrict__ b1_dg,  const float* __restrict__ wr_dg,  const float* __restrict__ br_dg,
    const _Float16* __restrict__ w1frag,
    float* __restrict__ d_out,
    _Float16* __restrict__ wsh)   // [0:1M) Achg f16 [ch][g], [1M:2M) AgdT f16 [d][g]
{
    __shared__ _Float16 hl_tile[LC * 128];       // 8 KB
    __shared__ float ybuf[64 * YSTRIDE];         // raw y values (8.25 KB)

    const int bz = blockIdx.z;
    const _Float16* HL = hlhr + (bz ? 262144 : 0);
    const _Float16* HR = hlhr + (bz ? 393216 : 131072);
    const float* b1 = bz ? b1_dg : b1_chg;
    const float* wr = bz ? wr_dg : wr_chg;
    const float brv = bz ? br_dg[0] : br_chg[0];
    float* outA = d_out + (bz ? 2097152 : 1048576);
    _Float16* outB = wsh + (bz ? 1048576 : 0);

    const int tid = threadIdx.x;
    const int lane = tid & 63, wave = tid >> 6;
    const int m = lane & 15, quad = lane >> 4;
    const int lbase = blockIdx.y * LC;
    const int rbase = blockIdx.x * 64;
    const int rm = rbase + wave * 16 + m;   // this lane's pair (column)
    const int p = wave * 16 + m;            // pair index within block

    {   // stage hl tile (fp16): LC*128 halves = 512 uint4
        const uint4* src = (const uint4*)(HL + lbase * 128);
        uint4* dst = (uint4*)hl_tile;
#pragma unroll
        for (int i = 0; i < 2; ++i)
            dst[tid + i * 256] = src[tid + i * 256];
    }

    // hr in B-frag k-order (fp16): k = ks*32 + quad*8 + j
    half8 hr16[4];
#pragma unroll
    for (int ks = 0; ks < 4; ++ks)
        hr16[ks] = *(const half8*)(HR + rm * 128 + ks * 32 + quad * 8);

    // W1^T A-fragments (constant across the loop)
    half8 w1f[4][4];   // [mt][ks]
    {
        const uint4* wf = (const uint4*)(w1frag + bz * 8192);
#pragma unroll
        for (int f = 0; f < 16; ++f) {
            U4H8 t; t.u = wf[f * 64 + lane];
            w1f[f >> 2][f & 3] = t.h;
        }
    }

    // per-lane n-slice constants: n = mt*16 + quad*4 + r
    floatx4 b1q[4];
    floatx2 wr2l[4], wr2h[4];
#pragma unroll
    for (int mt = 0; mt < 4; ++mt) {
        b1q[mt] = *(const floatx4*)(b1 + mt * 16 + quad * 4);
        floatx4 w4 = *(const floatx4*)(wr + mt * 16 + quad * 4);
        wr2l[mt] = __builtin_shufflevector(w4, w4, 0, 1);
        wr2h[mt] = __builtin_shufflevector(w4, w4, 2, 3);
    }

    const floatx2 z2 = (floatx2){0.f, 0.f};
    half8 hz;
#pragma unroll
    for (int j = 0; j < 8; ++j) hz[j] = (_Float16)0.f;

    __syncthreads();

#pragma unroll 2
    for (int li = 0; li < LC; ++li) {
        const _Float16* hlp = hl_tile + li * 128;

        // h = relu(hl16 + hr16) in packed fp16 -> B-fragments
        half8 bfr[4];
#pragma unroll
        for (int ks = 0; ks < 4; ++ks) {
            half8 hl8 = *(const half8*)(hlp + ks * 32 + quad * 8);
            bfr[ks] = __builtin_elementwise_max(hl8 + hr16[ks], hz);
        }

        floatx4 acc[4];
#pragma unroll
        for (int mt = 0; mt < 4; ++mt)
            acc[mt] = b1q[mt];   // b1 folded into the accumulator init
#pragma unroll
        for (int ks = 0; ks < 4; ++ks)
#pragma unroll
            for (int mt = 0; mt < 4; ++mt)
                acc[mt] = __builtin_amdgcn_mfma_f32_16x16x32_f16(w1f[mt][ks], bfr[ks], acc[mt], 0, 0, 0);

        // acc[mt][r] = h1[pair rm][n = mt*16+quad*4+r] + b1;  dot with Wr
        floatx2 y2 = z2;
#pragma unroll
        for (int mt = 0; mt < 4; ++mt) {
            floatx2 lo = __builtin_shufflevector(acc[mt], acc[mt], 0, 1);
            floatx2 hi = __builtin_shufflevector(acc[mt], acc[mt], 2, 3);
            y2 += __builtin_elementwise_max(lo, z2) * wr2l[mt];
            y2 += __builtin_elementwise_max(hi, z2) * wr2h[mt];
        }
        float y = y2[0] + y2[1];

        y += __shfl_xor(y, 16, 64);
        y += __shfl_xor(y, 32, 64);

        if (quad == 0)
            ybuf[p * YSTRIDE + li] = y;   // raw y; elu deferred to epilogue
    }

    __syncthreads();

    // ---- epilogue pass 1: [li][pp] order -> outA (both) + outB (bz==0)
    {
        int li = tid >> 3;            // 0..31
        int p0 = (tid & 7) * 8;       // 0,8,..,56
        float v[8];
#pragma unroll
        for (int j = 0; j < 8; ++j) {
            float yv = ybuf[(p0 + j) * YSTRIDE + li] + brv;
            v[j] = yv > 0.f ? yv : (expf(yv) - 1.f);   // elu
        }
        float4* dstA = (float4*)(outA + (lbase + li) * 1024 + rbase + p0);
        dstA[0] = make_float4(v[0], v[1], v[2], v[3]);
        dstA[1] = make_float4(v[4], v[5], v[6], v[7]);
        if (bz == 0) {
            PKH8 pk;
#pragma unroll
            for (int j = 0; j < 8; ++j) pk.h[j] = (_Float16)v[j];
            *(uint4*)(outB + (lbase + li) * 1024 + rbase + p0) = pk.u;
        }
    }
    // ---- epilogue pass 2 (bz==1): [pp][li] order -> AgdT transposed
    if (bz == 1) {
        int pp = tid >> 2;            // 0..63
        int li0 = (tid & 3) * 8;      // 0,8,16,24
        PKH8 pk;
#pragma unroll
        for (int j = 0; j < 8; ++j) {
            float yv = ybuf[pp * YSTRIDE + li0 + j] + brv;
            float v = yv > 0.f ? yv : (expf(yv) - 1.f);
            pk.h[j] = (_Float16)v;
        }
        *(uint4*)(outB + (rbase + pp) * 1024 + lbase + li0) = pk.u;
    }
}

// ---------------------------------------------------------------- final GEMM + sigmoid
// C[ch][d] = sum_g Achg[ch][g]*Agd[g][d]; fp16 MFMA, fp32 accum.
// 32x32 tiles, 1024 blocks; BK=128 per stage (8 barrier pairs), dual acc.
#define GSTRIDE 136   // halfwords; 2-way bank aliasing only (free)

__global__ __launch_bounds__(256) void gemm_sig(
    const _Float16* __restrict__ Ahf,   // [1024][1024] ch x g
    const _Float16* __restrict__ BThf,  // [1024][1024] d x g
    float* __restrict__ out0)
{
    __shared__ _Float16 At[32 * GSTRIDE];
    __shared__ _Float16 Bt[32 * GSTRIDE];

    const int tid = threadIdx.x, lane = tid & 63, wave = tid >> 6;
    const int m = lane & 15, quad = lane >> 4;
    const int chbase = blockIdx.y * 32, dbase = blockIdx.x * 32;
    const int wrow = (wave >> 1) * 16, wcol = (wave & 1) * 16;

    floatx4 acc0 = (floatx4){0.f, 0.f, 0.f, 0.f};
    floatx4 acc1 = (floatx4){0.f, 0.f, 0.f, 0.f};

    // staging: 32 rows x 16 uint4 per matrix = 512 uint4; 2 per thread
    uint4 ra[2], rb[2];
#pragma unroll
    for (int i = 0; i < 2; ++i) {
        int idx = tid + i * 256, rr = idx >> 4, cc = idx & 15;
        ra[i] = *(const uint4*)(Ahf + (chbase + rr) * 1024 + cc * 8);
        rb[i] = *(const uint4*)(BThf + (dbase + rr) * 1024 + cc * 8);
    }

    for (int kb = 0; kb < 1024; kb += 128) {
#pragma unroll
        for (int i = 0; i < 2; ++i) {
            int idx = tid + i * 256, rr = idx >> 4, cc = idx & 15;
            *(uint4*)(At + rr * GSTRIDE + cc * 8) = ra[i];
            *(uint4*)(Bt + rr * GSTRIDE + cc * 8) = rb[i];
        }
        __syncthreads();
        if (kb + 128 < 1024) {
#pragma unroll
            for (int i = 0; i < 2; ++i) {
                int idx = tid + i * 256, rr = idx >> 4, cc = idx & 15;
                ra[i] = *(const uint4*)(Ahf + (chbase + rr) * 1024 + kb + 128 + cc * 8);
                rb[i] = *(const uint4*)(BThf + (dbase + rr) * 1024 + kb + 128 + cc * 8);
            }
        }
#pragma unroll
        for (int k2 = 0; k2 < 4; ++k2) {
            int koff = k2 * 32 + quad * 8;
            half8 a = *(const half8*)(At + (wrow + m) * GSTRIDE + koff);
            half8 b = *(const half8*)(Bt + (wcol + m) * GSTRIDE + koff);
            if (k2 & 1)
                acc1 = __builtin_amdgcn_mfma_f32_16x16x32_f16(a, b, acc1, 0, 0, 0);
            else
                acc0 = __builtin_amdgcn_mfma_f32_16x16x32_f16(a, b, acc0, 0, 0, 0);
        }
        __syncthreads();
    }

    floatx4 acc = acc0 + acc1;
#pragma unroll
    for (int r = 0; r < 4; ++r) {
        int row_o = chbase + wrow + quad * 4 + r;
        int col_o = dbase + wcol + m;
        out0[row_o * 1024 + col_o] = 1.f / (1.f + expf(-acc[r]));
    }
}

// ---------------------------------------------------------------- launch
extern "C" void kernel_launch(void* const* d_in, const int* in_sizes, int n_in,
                              void* d_out, int out_size, void* d_ws, size_t ws_size,
                              hipStream_t stream) {
    const float* Xch = (const float*)d_in[0];
    const float* Xg  = (const float*)d_in[1];
    const float* Xd  = (const float*)d_in[2];
    const float* Wc0 = (const float*)d_in[3];
    const float* bc0 = (const float*)d_in[4];
    const float* Wc1 = (const float*)d_in[5];
    const float* bc1 = (const float*)d_in[6];
    const float* Wcr = (const float*)d_in[7];
    const float* bcr = (const float*)d_in[8];
    const float* Wd0 = (const float*)d_in[9];
    const float* bd0 = (const float*)d_in[10];
    const float* Wd1 = (const float*)d_in[11];
    const float* bd1 = (const float*)d_in[12];
    const float* Wdr = (const float*)d_in[13];
    const float* bdr = (const float*)d_in[14];

    float* out = (float*)d_out;
    _Float16* hlhr = (_Float16*)d_ws;            // 4x1024x128 fp16 = 1 MB
    _Float16* wsh = hlhr + 524288;               // Achg f16 1M + AgdT f16 1M
    _Float16* w1frag = wsh + 2097152;            // 16384 f16

    prep<<<2112, 256, 0, stream>>>(Xch, Xg, Xd, Wc0, bc0, Wd0, bd0, Wc1, Wd1,
                                   hlhr, w1frag);

    dim3 gb(16, 32, 2);   // (r-chunks of 64, l-chunks of 32, branch)
    branch_kernel<<<gb, 256, 0, stream>>>(hlhr, bc1, Wcr, bcr, bd1, Wdr, bdr,
                                          w1frag, out, wsh);

    dim3 gg(32, 32);
    gemm_sig<<<gg, 256, 0, stream>>>(wsh, wsh + 1048576, out);
}

// Round 13
// 134.520 us; speedup vs baseline: 1.1757x; 1.1757x over previous
//
#include <hip/hip_runtime.h>
#include <hip/hip_bf16.h>

// Two pairwise MLPs (ChG, DG) over 1024x1024 pairs, then A_chg @ A_gd, sigmoid.
// Outputs concat: [0:1M) sigmoid(A_chd), [1M:2M) A_chg, [2M:3M) A_gd (fp32).
//
// R13 = R12's branch (deferred-elu epilogue, 45.3us verified) + R9's gemm_sig
// (32x32 BK=64 dual-acc; R12's BK=128 retile regressed the residue 88->113us,
// likely an occupancy cliff from 2x per-stage LDS). prep unchanged.
// Numerics identical: absmax must stay exactly 0.03125.

typedef _Float16 half8 __attribute__((ext_vector_type(8)));
typedef float floatx4 __attribute__((ext_vector_type(4)));
typedef float floatx2 __attribute__((ext_vector_type(2)));

union U4H8 { uint4 u; half8 h; };
union PKH8 { uint4 u; _Float16 h[8]; };

// ---------------------------------------------------------------- prep
// blocks 0..2047: hlhr (fp16): seg0 HL_chg(+b0c), seg1 HR_chg,
//                 seg2 HL_dg(+b0d), seg3 HR_dg; each [1024][128]
// blocks 2048..2111: w1frag[br][f=mt*4+ks][lane][j] =
//                 f16( W1[ks*32+(lane>>4)*8+j][mt*16+(lane&15)] )  (A-layout of W1^T)
__global__ __launch_bounds__(256) void prep(
    const float* __restrict__ Xch, const float* __restrict__ Xg,
    const float* __restrict__ Xd,
    const float* __restrict__ Wc0, const float* __restrict__ bc0,
    const float* __restrict__ Wd0, const float* __restrict__ bd0,
    const float* __restrict__ W1c, const float* __restrict__ W1d,
    _Float16* __restrict__ hlhr, _Float16* __restrict__ w1frag)
{
    int bid = blockIdx.x;
    if (bid < 2048) {
        int t = bid * 256 + threadIdx.x;   // 524288 threads
        int seg = t >> 17;
        int i = (t >> 7) & 1023;
        int k = t & 127;
        const float* X;
        const float* W;
        float s = 0.f;
        int wo = 0;
        if (seg == 0)      { X = Xch; W = Wc0; s = bc0[k]; }
        else if (seg == 1) { X = Xg;  W = Wc0; wo = 5; }
        else if (seg == 2) { X = Xg;  W = Wd0; s = bd0[k]; }
        else               { X = Xd;  W = Wd0; wo = 5; }
#pragma unroll
        for (int j = 0; j < 5; ++j)
            s += X[i * 5 + j] * W[(wo + j) * 128 + k];
        hlhr[t] = (_Float16)s;   // fp32 dot, one RNE round to fp16
    } else {
        int t = (bid - 2048) * 256 + threadIdx.x;   // 16384 threads
        int br   = t >> 13;
        int f    = (t >> 9) & 15;
        int lane = (t >> 3) & 63;
        int j    = t & 7;
        int mt = f >> 2, ks = f & 3;
        int row = ks * 32 + (lane >> 4) * 8 + j;    // k of W1
        int col = mt * 16 + (lane & 15);            // n of W1
        const float* W = br ? W1d : W1c;
        w1frag[t] = (_Float16)W[row * 64 + col];
    }
}

// ---------------------------------------------------------------- branch
#define LC 32
#define YSTRIDE 33   // ybuf row stride in floats (conflict-free)

__global__ __launch_bounds__(256, 3) void branch_kernel(
    const _Float16* __restrict__ hlhr,
    const float* __restrict__ b1_chg, const float* __restrict__ wr_chg, const float* __restrict__ br_chg,
    const float* __restrict__ b1_dg,  const float* __restrict__ wr_dg,  const float* __restrict__ br_dg,
    const _Float16* __restrict__ w1frag,
    float* __restrict__ d_out,
    _Float16* __restrict__ wsh)   // [0:1M) Achg f16 [ch][g], [1M:2M) AgdT f16 [d][g]
{
    __shared__ _Float16 hl_tile[LC * 128];       // 8 KB
    __shared__ float ybuf[64 * YSTRIDE];         // raw y values (8.25 KB)

    const int bz = blockIdx.z;
    const _Float16* HL = hlhr + (bz ? 262144 : 0);
    const _Float16* HR = hlhr + (bz ? 393216 : 131072);
    const float* b1 = bz ? b1_dg : b1_chg;
    const float* wr = bz ? wr_dg : wr_chg;
    const float brv = bz ? br_dg[0] : br_chg[0];
    float* outA = d_out + (bz ? 2097152 : 1048576);
    _Float16* outB = wsh + (bz ? 1048576 : 0);

    const int tid = threadIdx.x;
    const int lane = tid & 63, wave = tid >> 6;
    const int m = lane & 15, quad = lane >> 4;
    const int lbase = blockIdx.y * LC;
    const int rbase = blockIdx.x * 64;
    const int rm = rbase + wave * 16 + m;   // this lane's pair (column)
    const int p = wave * 16 + m;            // pair index within block

    {   // stage hl tile (fp16): LC*128 halves = 512 uint4
        const uint4* src = (const uint4*)(HL + lbase * 128);
        uint4* dst = (uint4*)hl_tile;
#pragma unroll
        for (int i = 0; i < 2; ++i)
            dst[tid + i * 256] = src[tid + i * 256];
    }

    // hr in B-frag k-order (fp16): k = ks*32 + quad*8 + j
    half8 hr16[4];
#pragma unroll
    for (int ks = 0; ks < 4; ++ks)
        hr16[ks] = *(const half8*)(HR + rm * 128 + ks * 32 + quad * 8);

    // W1^T A-fragments (constant across the loop)
    half8 w1f[4][4];   // [mt][ks]
    {
        const uint4* wf = (const uint4*)(w1frag + bz * 8192);
#pragma unroll
        for (int f = 0; f < 16; ++f) {
            U4H8 t; t.u = wf[f * 64 + lane];
            w1f[f >> 2][f & 3] = t.h;
        }
    }

    // per-lane n-slice constants: n = mt*16 + quad*4 + r
    floatx4 b1q[4];
    floatx2 wr2l[4], wr2h[4];
#pragma unroll
    for (int mt = 0; mt < 4; ++mt) {
        b1q[mt] = *(const floatx4*)(b1 + mt * 16 + quad * 4);
        floatx4 w4 = *(const floatx4*)(wr + mt * 16 + quad * 4);
        wr2l[mt] = __builtin_shufflevector(w4, w4, 0, 1);
        wr2h[mt] = __builtin_shufflevector(w4, w4, 2, 3);
    }

    const floatx2 z2 = (floatx2){0.f, 0.f};
    half8 hz;
#pragma unroll
    for (int j = 0; j < 8; ++j) hz[j] = (_Float16)0.f;

    __syncthreads();

#pragma unroll 2
    for (int li = 0; li < LC; ++li) {
        const _Float16* hlp = hl_tile + li * 128;

        // h = relu(hl16 + hr16) in packed fp16 -> B-fragments
        half8 bfr[4];
#pragma unroll
        for (int ks = 0; ks < 4; ++ks) {
            half8 hl8 = *(const half8*)(hlp + ks * 32 + quad * 8);
            bfr[ks] = __builtin_elementwise_max(hl8 + hr16[ks], hz);
        }

        floatx4 acc[4];
#pragma unroll
        for (int mt = 0; mt < 4; ++mt)
            acc[mt] = b1q[mt];   // b1 folded into the accumulator init
#pragma unroll
        for (int ks = 0; ks < 4; ++ks)
#pragma unroll
            for (int mt = 0; mt < 4; ++mt)
                acc[mt] = __builtin_amdgcn_mfma_f32_16x16x32_f16(w1f[mt][ks], bfr[ks], acc[mt], 0, 0, 0);

        // acc[mt][r] = h1[pair rm][n = mt*16+quad*4+r] + b1;  dot with Wr
        floatx2 y2 = z2;
#pragma unroll
        for (int mt = 0; mt < 4; ++mt) {
            floatx2 lo = __builtin_shufflevector(acc[mt], acc[mt], 0, 1);
            floatx2 hi = __builtin_shufflevector(acc[mt], acc[mt], 2, 3);
            y2 += __builtin_elementwise_max(lo, z2) * wr2l[mt];
            y2 += __builtin_elementwise_max(hi, z2) * wr2h[mt];
        }
        float y = y2[0] + y2[1];

        y += __shfl_xor(y, 16, 64);
        y += __shfl_xor(y, 32, 64);

        if (quad == 0)
            ybuf[p * YSTRIDE + li] = y;   // raw y; elu deferred to epilogue
    }

    __syncthreads();

    // ---- epilogue pass 1: [li][pp] order -> outA (both) + outB (bz==0)
    {
        int li = tid >> 3;            // 0..31
        int p0 = (tid & 7) * 8;       // 0,8,..,56
        float v[8];
#pragma unroll
        for (int j = 0; j < 8; ++j) {
            float yv = ybuf[(p0 + j) * YSTRIDE + li] + brv;
            v[j] = yv > 0.f ? yv : (expf(yv) - 1.f);   // elu
        }
        float4* dstA = (float4*)(outA + (lbase + li) * 1024 + rbase + p0);
        dstA[0] = make_float4(v[0], v[1], v[2], v[3]);
        dstA[1] = make_float4(v[4], v[5], v[6], v[7]);
        if (bz == 0) {
            PKH8 pk;
#pragma unroll
            for (int j = 0; j < 8; ++j) pk.h[j] = (_Float16)v[j];
            *(uint4*)(outB + (lbase + li) * 1024 + rbase + p0) = pk.u;
        }
    }
    // ---- epilogue pass 2 (bz==1): [pp][li] order -> AgdT transposed
    if (bz == 1) {
        int pp = tid >> 2;            // 0..63
        int li0 = (tid & 3) * 8;      // 0,8,16,24
        PKH8 pk;
#pragma unroll
        for (int j = 0; j < 8; ++j) {
            float yv = ybuf[pp * YSTRIDE + li0 + j] + brv;
            float v = yv > 0.f ? yv : (expf(yv) - 1.f);
            pk.h[j] = (_Float16)v;
        }
        *(uint4*)(outB + (rbase + pp) * 1024 + lbase + li0) = pk.u;
    }
}

// ---------------------------------------------------------------- final GEMM + sigmoid
// C[ch][d] = sum_g Achg[ch][g]*Agd[g][d]; fp16 MFMA, fp32 accum.
// 32x32 tiles, 1024 blocks (4/CU); dual accumulator. (R9's version — BK=64.)
__global__ __launch_bounds__(256) void gemm_sig(
    const _Float16* __restrict__ Ahf,   // [1024][1024] ch x g
    const _Float16* __restrict__ BThf,  // [1024][1024] d x g
    float* __restrict__ out0)
{
    __shared__ _Float16 At[32 * 72];   // +8 pad
    __shared__ _Float16 Bt[32 * 72];

    const int tid = threadIdx.x, lane = tid & 63, wave = tid >> 6;
    const int m = lane & 15, quad = lane >> 4;
    const int chbase = blockIdx.y * 32, dbase = blockIdx.x * 32;
    const int wrow = (wave >> 1) * 16, wcol = (wave & 1) * 16;

    floatx4 acc0 = (floatx4){0.f, 0.f, 0.f, 0.f};
    floatx4 acc1 = (floatx4){0.f, 0.f, 0.f, 0.f};

    const int row = tid >> 3, c4 = tid & 7;   // 32 rows x 8 uint4 = 256 threads
    uint4 ra = *(const uint4*)(Ahf + (chbase + row) * 1024 + c4 * 8);
    uint4 rb = *(const uint4*)(BThf + (dbase + row) * 1024 + c4 * 8);

    for (int kb = 0; kb < 1024; kb += 64) {
        *(uint4*)(At + row * 72 + c4 * 8) = ra;
        *(uint4*)(Bt + row * 72 + c4 * 8) = rb;
        __syncthreads();
        if (kb + 64 < 1024) {
            ra = *(const uint4*)(Ahf + (chbase + row) * 1024 + kb + 64 + c4 * 8);
            rb = *(const uint4*)(BThf + (dbase + row) * 1024 + kb + 64 + c4 * 8);
        }
        {
            half8 a0 = *(const half8*)(At + (wrow + m) * 72 + quad * 8);
            half8 b0 = *(const half8*)(Bt + (wcol + m) * 72 + quad * 8);
            half8 a1 = *(const half8*)(At + (wrow + m) * 72 + 32 + quad * 8);
            half8 b1 = *(const half8*)(Bt + (wcol + m) * 72 + 32 + quad * 8);
            acc0 = __builtin_amdgcn_mfma_f32_16x16x32_f16(a0, b0, acc0, 0, 0, 0);
            acc1 = __builtin_amdgcn_mfma_f32_16x16x32_f16(a1, b1, acc1, 0, 0, 0);
        }
        __syncthreads();
    }

    floatx4 acc = acc0 + acc1;
#pragma unroll
    for (int r = 0; r < 4; ++r) {
        int row_o = chbase + wrow + quad * 4 + r;
        int col_o = dbase + wcol + m;
        out0[row_o * 1024 + col_o] = 1.f / (1.f + expf(-acc[r]));
    }
}

// ---------------------------------------------------------------- launch
extern "C" void kernel_launch(void* const* d_in, const int* in_sizes, int n_in,
                              void* d_out, int out_size, void* d_ws, size_t ws_size,
                              hipStream_t stream) {
    const float* Xch = (const float*)d_in[0];
    const float* Xg  = (const float*)d_in[1];
    const float* Xd  = (const float*)d_in[2];
    const float* Wc0 = (const float*)d_in[3];
    const float* bc0 = (const float*)d_in[4];
    const float* Wc1 = (const float*)d_in[5];
    const float* bc1 = (const float*)d_in[6];
    const float* Wcr = (const float*)d_in[7];
    const float* bcr = (const float*)d_in[8];
    const float* Wd0 = (const float*)d_in[9];
    const float* bd0 = (const float*)d_in[10];
    const float* Wd1 = (const float*)d_in[11];
    const float* bd1 = (const float*)d_in[12];
    const float* Wdr = (const float*)d_in[13];
    const float* bdr = (const float*)d_in[14];

    float* out = (float*)d_out;
    _Float16* hlhr = (_Float16*)d_ws;            // 4x1024x128 fp16 = 1 MB
    _Float16* wsh = hlhr + 524288;               // Achg f16 1M + AgdT f16 1M
    _Float16* w1frag = wsh + 2097152;            // 16384 f16

    prep<<<2112, 256, 0, stream>>>(Xch, Xg, Xd, Wc0, bc0, Wd0, bd0, Wc1, Wd1,
                                   hlhr, w1frag);

    dim3 gb(16, 32, 2);   // (r-chunks of 64, l-chunks of 32, branch)
    branch_kernel<<<gb, 256, 0, stream>>>(hlhr, bc1, Wcr, bcr, bd1, Wdr, bdr,
                                          w1frag, out, wsh);

    dim3 gg(32, 32);
    gemm_sig<<<gg, 256, 0, stream>>>(wsh, wsh + 1048576, out);
}